// Round 8
// baseline (192.679 us; speedup 1.0000x reference)
//
#include <hip/hip_runtime.h>
#include <hip/hip_bf16.h>

// Sizes (fixed by the problem)
#define B_   2
#define LQ_  2048
#define LK_  2048
#define QDIM_ 1024
#define KDIM_ 768
#define VDIM_ 768
#define HID_ 1024
#define H_   16
#define D_   64   // head dim

typedef unsigned short ushort_t;
typedef __attribute__((ext_vector_type(8))) short short8v;   // 8 bf16 MFMA A/B frag
typedef __attribute__((ext_vector_type(4))) float f32x4;     // MFMA C/D frag

__device__ __forceinline__ float bf2f(unsigned short u) {
    union { unsigned int i; float f; } x; x.i = ((unsigned int)u) << 16; return x.f;
}
__device__ __forceinline__ unsigned short f2bf(float f) {
    union { float f; unsigned int i; } x; x.f = f;
    unsigned int r = x.i + 0x7FFFu + ((x.i >> 16) & 1u);  // RNE
    return (unsigned short)(r >> 16);
}
__device__ __forceinline__ float exp2_(float x) {
#if defined(__has_builtin) && __has_builtin(__builtin_amdgcn_exp2f)
    return __builtin_amdgcn_exp2f(x);
#else
    return __expf(x * 0.69314718055994531f);
#endif
}
__device__ __forceinline__ unsigned cvtpk_bf16(float lo, float hi) {
    unsigned r;
    asm("v_cvt_pk_bf16_f32 %0, %1, %2" : "=v"(r) : "v"(lo), "v"(hi));
    return r;
}
__device__ __forceinline__ unsigned perm_b32(unsigned hi, unsigned lo, unsigned sel) {
#if defined(__has_builtin) && __has_builtin(__builtin_amdgcn_perm)
    return __builtin_amdgcn_perm(hi, lo, sel);
#else
    unsigned r = 0;
    for (int i = 0; i < 4; ++i) {
        unsigned s = (sel >> (8 * i)) & 0xFF;
        unsigned byte = (s < 4) ? ((lo >> (8 * s)) & 0xFF) : ((hi >> (8 * (s - 4))) & 0xFF);
        r |= byte << (8 * i);
    }
    return r;
#endif
}
// global -> LDS direct (16B per lane). Fallback: plain copy.
__device__ __forceinline__ void stage16(const ushort_t* g, ushort_t* l) {
#if defined(__has_builtin) && __has_builtin(__builtin_amdgcn_global_load_lds)
    __builtin_amdgcn_global_load_lds(
        (const __attribute__((address_space(1))) unsigned*)g,
        (__attribute__((address_space(3))) unsigned*)l, 16, 0, 0);
#else
    *(uint4*)l = *(const uint4*)g;
#endif
}

// ---------------------------------------------------------------------------
// Runtime dtype detection (flag=1 -> inputs bf16, flag=0 -> f32).
// ---------------------------------------------------------------------------
__global__ void detect_dtype(const ushort_t* __restrict__ q, int* __restrict__ flag) {
    const int tid = threadIdx.x;
    float m = 0.f;
    for (int i = tid; i < 4096; i += 64) m = fmaxf(m, fabsf(bf2f(q[i])));
    #pragma unroll
    for (int off = 1; off < 64; off <<= 1) m = fmaxf(m, __shfl_xor(m, off));
    if (tid == 0) flag[0] = (m < 1000.0f) ? 1 : 0;
}

// ---------------------------------------------------------------------------
// Fused 4-way transpose: op z: W[R][1024] (f32/bf16 per flag) -> WT[1024][R].
// ops: 0=Wq(R=1024) 1=Wk(768) 2=Wv(768) 3=Wo(1024)
// ---------------------------------------------------------------------------
__global__ __launch_bounds__(256) void transpose4(
    const void* __restrict__ W0, const void* __restrict__ W1,
    const void* __restrict__ W2, const void* __restrict__ W3,
    ushort_t* __restrict__ O0, ushort_t* __restrict__ O1,
    ushort_t* __restrict__ O2, ushort_t* __restrict__ O3,
    const int* __restrict__ flagp)
{
    __shared__ ushort_t tile[32][33];
    const int isbf = flagp[0];
    const int op = blockIdx.z;
    const void* in = (op == 0) ? W0 : (op == 1) ? W1 : (op == 2) ? W2 : W3;
    ushort_t* out  = (op == 0) ? O0 : (op == 1) ? O1 : (op == 2) ? O2 : O3;
    const int R = (op == 1 || op == 2) ? KDIM_ : 1024;
    const int C = 1024;
    const int tx = threadIdx.x & 31;
    const int ty = threadIdx.x >> 5;
    const int r0 = blockIdx.y * 32, c0 = blockIdx.x * 32;
    if (r0 >= R) return;
    #pragma unroll
    for (int j = 0; j < 4; ++j) {
        int r = r0 + ty + j * 8;
        ushort_t v;
        if (isbf) v = ((const ushort_t*)in)[(size_t)r * C + c0 + tx];
        else      v = f2bf(((const float*)in)[(size_t)r * C + c0 + tx]);
        tile[ty + j * 8][tx] = v;
    }
    __syncthreads();
    #pragma unroll
    for (int j = 0; j < 4; ++j) {
        int c = c0 + ty + j * 8;
        out[(size_t)c * R + r0 + tx] = tile[tx][ty + j * 8];
    }
}

// ---------------------------------------------------------------------------
// GEMM core, 2-phase double-buffered, tile 128xTBN, BK=32, 256 thr = 4 waves
// (2x2), wave tile 64x(TBN/2). LDS XOR-swizzled (row&3 on 8-col chunks):
// pre-swizzled gload_lds source, swizzled reads.
// ---------------------------------------------------------------------------
template<int TBN>
__device__ __forceinline__ void gemm_core(
    const void* __restrict__ A, const ushort_t* __restrict__ WT,
    const void* __restrict__ bias, void* __restrict__ Cp,
    int M, int N, int K, int isbf, int a_bf, int c_bf, float out_scale,
    int wg, ushort_t (*As)[32], ushort_t (*Bs)[32])
{
    constexpr int NF = TBN / 32;              // B frags per wave
    const int tid = threadIdx.x;
    const int l = tid & 63, w = tid >> 6;
    const int g = l >> 4, q = l & 15;
    const int wr = (w >> 1) * 64, wc = (w & 1) * (TBN / 2);
    const int nbn = N / TBN;
    const int bm = (wg / nbn) * 128;
    const int bn = (wg % nbn) * TBN;

    const int r_ = tid >> 2;                    // 0..63
    const int c_ = tid & 3;                     // 8-col chunk
    const int sc_ = ((c_ ^ (r_ & 3)) << 3);     // swizzled col
    const int dc_ = c_ << 3;

    f32x4 acc[4][NF];
    #pragma unroll
    for (int i = 0; i < 4; ++i)
        #pragma unroll
        for (int j = 0; j < NF; ++j)
            acc[i][j] = (f32x4){0.f, 0.f, 0.f, 0.f};

    const int NT = K >> 5;
    float4 fA[4];

    auto issue = [&](int t, int buf) {
        const int koff = t << 5;
        if (a_bf) {
            stage16((const ushort_t*)A + (size_t)(bm + r_) * K + koff + sc_,
                    &As[(buf << 7) + r_][dc_]);
            stage16((const ushort_t*)A + (size_t)(bm + 64 + r_) * K + koff + sc_,
                    &As[(buf << 7) + 64 + r_][dc_]);
        } else {
            const float* Af0 = (const float*)A + (size_t)(bm + r_) * K + koff + dc_;
            const float* Af1 = (const float*)A + (size_t)(bm + 64 + r_) * K + koff + dc_;
            fA[0] = *(const float4*)Af0; fA[1] = *(const float4*)(Af0 + 4);
            fA[2] = *(const float4*)Af1; fA[3] = *(const float4*)(Af1 + 4);
        }
        stage16(WT + (size_t)(bn + r_) * K + koff + sc_, &Bs[buf * TBN + r_][dc_]);
        if (TBN == 128)
            stage16(WT + (size_t)(bn + 64 + r_) * K + koff + sc_, &Bs[buf * TBN + 64 + r_][dc_]);
    };
    auto commitA = [&](int buf) {
        ushort_t t0[8], t1[8];
        t0[0]=f2bf(fA[0].x); t0[1]=f2bf(fA[0].y); t0[2]=f2bf(fA[0].z); t0[3]=f2bf(fA[0].w);
        t0[4]=f2bf(fA[1].x); t0[5]=f2bf(fA[1].y); t0[6]=f2bf(fA[1].z); t0[7]=f2bf(fA[1].w);
        t1[0]=f2bf(fA[2].x); t1[1]=f2bf(fA[2].y); t1[2]=f2bf(fA[2].z); t1[3]=f2bf(fA[2].w);
        t1[4]=f2bf(fA[3].x); t1[5]=f2bf(fA[3].y); t1[6]=f2bf(fA[3].z); t1[7]=f2bf(fA[3].w);
        *(uint4*)&As[(buf << 7) + r_][sc_]      = *(uint4*)t0;
        *(uint4*)&As[(buf << 7) + 64 + r_][sc_] = *(uint4*)t1;
    };

    issue(0, 0);
    if (!a_bf) commitA(0);
    __syncthreads();

    int cur = 0;
    const int fcol = ((g ^ (q & 3)) << 3);   // frag read col (swizzled)
    for (int t = 0; t < NT; ++t) {
        const bool has = (t + 1 < NT);
        if (has) issue(t + 1, cur ^ 1);

        short8v a[4], bb[NF];
        #pragma unroll
        for (int mf = 0; mf < 4; ++mf)
            a[mf] = *(const short8v*)&As[(cur << 7) + wr + mf * 16 + q][fcol];
        #pragma unroll
        for (int nf = 0; nf < NF; ++nf)
            bb[nf] = *(const short8v*)&Bs[cur * TBN + wc + nf * 16 + q][fcol];
        #pragma unroll
        for (int mf = 0; mf < 4; ++mf)
            #pragma unroll
            for (int nf = 0; nf < NF; ++nf)
                acc[mf][nf] = __builtin_amdgcn_mfma_f32_16x16x32_bf16(a[mf], bb[nf], acc[mf][nf], 0, 0, 0);

        if (has && !a_bf) commitA(cur ^ 1);
        __syncthreads();
        cur ^= 1;
    }

    // epilogue: D layout col=lane&15, row=(lane>>4)*4+reg
    float bv[NF];
    #pragma unroll
    for (int nf = 0; nf < NF; ++nf) {
        int col = bn + wc + nf * 16 + q;
        bv[nf] = isbf ? bf2f(((const ushort_t*)bias)[col]) : ((const float*)bias)[col];
    }
    #pragma unroll
    for (int mf = 0; mf < 4; ++mf)
        #pragma unroll
        for (int nf = 0; nf < NF; ++nf)
            #pragma unroll
            for (int reg = 0; reg < 4; ++reg) {
                int row = bm + wr + mf * 16 + g * 4 + reg;
                int col = bn + wc + nf * 16 + q;
                float vv = (acc[mf][nf][reg] + bv[nf]) * out_scale;
                if (c_bf) ((ushort_t*)Cp)[(size_t)row * N + col] = f2bf(vv);
                else      ((float*)Cp)[(size_t)row * N + col] = vv;
            }
}

struct G3 {
    const void* A0; const void* A1; const void* A2;
    const ushort_t* W0; const ushort_t* W1; const ushort_t* W2;
    const void* b0; const void* b1; const void* b2;
    void* C0; void* C1; void* C2;
    int K0, K1, K2;
    float s0, s1, s2;
};

// fused Q/K/V projections: grid (256, 3); blockIdx.y picks the op
__global__ __launch_bounds__(256) void gemm3_mfma(G3 p, int M, int N,
                                                  const int* __restrict__ flagp)
{
    __shared__ ushort_t As[2 * 128][32];
    __shared__ ushort_t Bs[2 * 128][32];
    const int isbf = flagp[0];
    const int op = blockIdx.y;
    const void* A = (op == 0) ? p.A0 : (op == 1) ? p.A1 : p.A2;
    const ushort_t* WT = (op == 0) ? p.W0 : (op == 1) ? p.W1 : p.W2;
    const void* bias = (op == 0) ? p.b0 : (op == 1) ? p.b1 : p.b2;
    void* C = (op == 0) ? p.C0 : (op == 1) ? p.C1 : p.C2;
    const int K = (op == 0) ? p.K0 : (op == 1) ? p.K1 : p.K2;
    const float sc = (op == 0) ? p.s0 : (op == 1) ? p.s1 : p.s2;
    const int cpx = gridDim.x >> 3;
    const int wg = (blockIdx.x & 7) * cpx + (blockIdx.x >> 3);
    gemm_core<128>(A, WT, bias, C, M, N, K, isbf, isbf, 1, sc, wg, As, Bs);
}

// O-projection: tile 128x64 -> 512 blocks = 2 blocks/CU
__global__ __launch_bounds__(256) void gemm_one(
    const void* __restrict__ A, const ushort_t* __restrict__ WT,
    const void* __restrict__ bias, void* __restrict__ Cp,
    int M, int N, int K, const int* __restrict__ flagp, float out_scale)
{
    __shared__ ushort_t As[2 * 128][32];
    __shared__ ushort_t Bs[2 * 64][32];
    const int isbf = flagp[0];
    const int cpx = gridDim.x >> 3;
    const int wg = (blockIdx.x & 7) * cpx + (blockIdx.x >> 3);
    gemm_core<64>(A, WT, bias, Cp, M, N, K, isbf, 1, isbf, out_scale, wg, As, Bs);
}

// ---------------------------------------------------------------------------
// MFMA flash attention. 512 thr = 8 waves; block = 128 q-rows; KV tiles 64.
// Q loaded DIRECTLY to registers (no sQ -> LDS 48KB -> 3 blocks/CU).
// V prefetched 2 tiles deep in registers (loop unrolled x2 for static sets).
// Swapped S^T = K.Q^T; PV O^T = V^T.P^T (lane-local softmax rows). Masking
// via packed-halfword AND (shift-invariant raw-score max). Denominator via
// ones-A-frag MFMA. Q pre-scaled by 0.125*log2(e). OUTPUT WRITTEN IN-PLACE
// over Q (each block writes exactly the (rows, head) only it reads).
// query_mask masks the KEY axis; key_mask masks the QUERY axis (faithful).
// ---------------------------------------------------------------------------
__global__ __launch_bounds__(512, 6) void attn_mfma(
    const ushort_t* __restrict__ Q, const ushort_t* __restrict__ Kp,
    const ushort_t* __restrict__ Vp, const int* __restrict__ qmask,
    const int* __restrict__ kmask, ushort_t* __restrict__ ctx)   // ctx aliases Q
{
    __shared__ ushort_t sK[2][64][64];
    __shared__ ushort_t sVt[2][64][64];   // [d][key], swizzled
    __shared__ ushort_t sP[8][16][64];    // per-wave P, swizzled
    __shared__ unsigned sMaskPk[2][32];   // packed halfword mask per key-pair

    const int tid = threadIdx.x;
    const int l = tid & 63, w = tid >> 6;   // 8 waves
    const int g = l >> 4, q = l & 15;
    const int b = blockIdx.z, h = blockIdx.y;
    const int q0 = blockIdx.x * 128;
    const size_t hoff = (size_t)h * 64;
    const int swz = (q & 7) << 3;

    // V staging map: 256 pair-chunks (2 keys x 8 d), split across 2 threads
    const int vpi = tid & 255;
    const int vk2 = (vpi & 31) * 2;
    const int vdb = vpi >> 5;             // 0..7
    const int vds = (tid >> 8) * 4;       // 0 or 4
    const size_t vbase0 = ((size_t)(b * LK_) + vk2) * HID_ + hoff + vdb * 8 + vds;

    const int krow = tid >> 3, ks = tid & 7;
    const int kscol = ((ks ^ (krow & 7)) << 3);
    const size_t kbase0 = ((size_t)(b * LK_) + krow) * HID_ + hoff + kscol;

    const int myq = 16 * w + q;
    // Q direct to registers (16 elems/lane of its own row)
    const ushort_t* Qrow = Q + ((size_t)(b * LQ_) + q0 + myq) * HID_ + hoff;
    short8v qf0 = *(const short8v*)(Qrow + g * 8);
    short8v qf1 = *(const short8v*)(Qrow + 32 + g * 8);
    const int rowm = kmask[b * LK_ + q0 + myq];

    auto loadV = [&](int t, uint2& a, uint2& c) {
        size_t base = vbase0 + (size_t)t * 64 * HID_;
        a = *(const uint2*)(Vp + base);
        c = *(const uint2*)(Vp + base + HID_);
    };
    auto writeV = [&](int buf, uint2 a, uint2 c) {
        #pragma unroll
        for (int t2 = 0; t2 < 2; ++t2) {
            unsigned d0w = t2 ? a.y : a.x;
            unsigned d1w = t2 ? c.y : c.x;
            unsigned lo = perm_b32(d1w, d0w, 0x05040100);
            unsigned hi = perm_b32(d1w, d0w, 0x07060302);
            int dr0 = vdb * 8 + vds + 2 * t2, dr1 = dr0 + 1;
            *(unsigned*)&sVt[buf][dr0][vk2 ^ ((dr0 & 7) << 3)] = lo;
            *(unsigned*)&sVt[buf][dr1][vk2 ^ ((dr1 & 7) << 3)] = hi;
        }
    };
    auto stageK = [&](int t, int buf) {
        stage16(Kp + kbase0 + (size_t)t * 64 * HID_, &sK[buf][krow][ks << 3]);
    };
    auto stageMask = [&](int t, int buf) {
        if (w == 0) {
            unsigned long long bits = __ballot(qmask[b * LQ_ + t * 64 + l] != 0);
            if (l < 32) {
                unsigned dw = (((bits >> (2 * l)) & 1ull) ? 0xFFFFu : 0u)
                            | (((bits >> (2 * l + 1)) & 1ull) ? 0xFFFF0000u : 0u);
                sMaskPk[buf][l] = dw;
            }
        }
    };

    // ---- prologue: tile 0 direct; V(1) into register set A ----
    uint2 vA0, vA1, vB0, vB1;
    {
        uint2 a, c;
        loadV(0, a, c);
        writeV(0, a, c);
    }
    stageK(0, 0);
    stageMask(0, 0);
    loadV(1, vA0, vA1);
    __syncthreads();

    short8v ones;
    #pragma unroll
    for (int j = 0; j < 8; ++j) ones[j] = (short)0x3F80;   // 1.0bf16

    float m_run = -1e30f;
    f32x4 o[4], o4;
    #pragma unroll
    for (int df = 0; df < 4; ++df) o[df] = (f32x4){0.f, 0.f, 0.f, 0.f};
    o4 = (f32x4){0.f, 0.f, 0.f, 0.f};

    auto step = [&](int t, int curb, uint2& wv0, uint2& wv1, uint2& iv0, uint2& iv1) {
        const bool hasW = (t + 1 < 32);
        const bool hasI = (t + 2 < 32);
        if (hasI) loadV(t + 2, iv0, iv1);             // 2-deep V prefetch
        if (hasW) { stageK(t + 1, curb ^ 1); stageMask(t + 1, curb ^ 1); }

        // ---- S^T = K . Q^T on buffer curb ----
        f32x4 s4[4];
        #pragma unroll
        for (int kf = 0; kf < 4; ++kf) s4[kf] = (f32x4){0.f, 0.f, 0.f, 0.f};
        #pragma unroll
        for (int kf = 0; kf < 4; ++kf) {
            short8v k0f = *(const short8v*)&sK[curb][kf * 16 + q][(g << 3) ^ swz];
            short8v k1f = *(const short8v*)&sK[curb][kf * 16 + q][(32 + (g << 3)) ^ swz];
            s4[kf] = __builtin_amdgcn_mfma_f32_16x16x32_bf16(k0f, qf0, s4[kf], 0, 0, 0);
            s4[kf] = __builtin_amdgcn_mfma_f32_16x16x32_bf16(k1f, qf1, s4[kf], 0, 0, 0);
        }

        // ---- online softmax on RAW scores (mask applied later to P) ----
        float tmx[8];
        #pragma unroll
        for (int i = 0; i < 8; ++i) tmx[i] = fmaxf(s4[i >> 2][i & 3], s4[2 + (i >> 2)][i & 3]);
        #pragma unroll
        for (int st = 4; st >= 1; st >>= 1)
            #pragma unroll
            for (int i = 0; i < st; ++i) tmx[i] = fmaxf(tmx[i], tmx[i + st]);
        float lm = tmx[0];
        lm = fmaxf(lm, __shfl_xor(lm, 16));
        lm = fmaxf(lm, __shfl_xor(lm, 32));

        const bool fullp = __any(lm - m_run > 8.0f) != 0;   // defer-max (T13)
        float mnew, corr;
        if (fullp) { mnew = fmaxf(m_run, lm); corr = exp2_(m_run - mnew); }
        else       { mnew = m_run;            corr = 1.0f; }

        #pragma unroll
        for (int kf = 0; kf < 4; ++kf)
            #pragma unroll
            for (int reg = 0; reg < 4; ++reg)
                s4[kf][reg] = exp2_(s4[kf][reg] - mnew);    // P in-place (saves VGPR)
        m_run = mnew;

        #pragma unroll
        for (int kf = 0; kf < 4; ++kf) {
            uint2 pv;
            pv.x = cvtpk_bf16(s4[kf][0], s4[kf][1]);
            pv.y = cvtpk_bf16(s4[kf][2], s4[kf][3]);
            *(uint2*)&sP[w][q][(kf * 16 + g * 4) ^ swz] = pv;
        }

        if (fullp) {   // lane-local rescale (O^T layout: no shuffles)
            #pragma unroll
            for (int df = 0; df < 4; ++df)
                #pragma unroll
                for (int reg = 0; reg < 4; ++reg) o[df][reg] *= corr;
            #pragma unroll
            for (int reg = 0; reg < 4; ++reg) o4[reg] *= corr;
        }

        // ---- PV (swapped): O^T = V^T . P_masked^T ; denom via ones A-frag ----
        #pragma unroll
        for (int s2 = 0; s2 < 2; ++s2) {
            uint4 paw = *(const uint4*)&sP[w][q][((s2 * 32) + (g << 3)) ^ swz];
            uint4 mk = *(const uint4*)&sMaskPk[curb][s2 * 16 + g * 4];
            paw.x &= mk.x; paw.y &= mk.y; paw.z &= mk.z; paw.w &= mk.w;
            short8v pa;
            __builtin_memcpy(&pa, &paw, 16);
            #pragma unroll
            for (int df = 0; df < 4; ++df) {
                short8v vb = *(const short8v*)&sVt[curb][df * 16 + q][((s2 * 32) + (g << 3)) ^ swz];
                o[df] = __builtin_amdgcn_mfma_f32_16x16x32_bf16(vb, pa, o[df], 0, 0, 0);
            }
            o4 = __builtin_amdgcn_mfma_f32_16x16x32_bf16(ones, pa, o4, 0, 0, 0);
        }

        if (hasW) writeV(curb ^ 1, wv0, wv1);   // write-late: V(t+1), loaded a step ago
        __syncthreads();
    };

    for (int t2 = 0; t2 < 32; t2 += 2) {
        step(t2,     0, vA0, vA1, vB0, vB1);
        step(t2 + 1, 1, vB0, vB1, vA0, vA1);
    }

    // ---- epilogue: outputs belong to row myq; denom lane-local in o4 ----
    const float lr = o4[0];
    const float lqv = (rowm != 0 && lr > 0.f) ? (1.f / lr) : 0.f;
    ushort_t* orow = ctx + ((size_t)(b * LQ_) + q0 + myq) * HID_ + hoff;
    #pragma unroll
    for (int df = 0; df < 4; ++df) {
        uint2 st;
        st.x = cvtpk_bf16(o[df][0] * lqv, o[df][1] * lqv);
        st.y = cvtpk_bf16(o[df][2] * lqv, o[df][3] * lqv);
        *(uint2*)(orow + df * 16 + g * 4) = st;
    }
}

// ---------------------------------------------------------------------------
extern "C" void kernel_launch(void* const* d_in, const int* in_sizes, int n_in,
                              void* d_out, int out_size, void* d_ws, size_t ws_size,
                              hipStream_t stream) {
    const int* qmask = (const int*)d_in[11];
    const int* kmask = (const int*)d_in[12];

    const size_t M = (size_t)B_ * LQ_;      // 4096
    int* flag = (int*)d_ws;
    ushort_t* qx = (ushort_t*)((char*)d_ws + 256);   // Q-proj out, then ctx (in-place)
    ushort_t* kx = qx + M * HID_;
    ushort_t* vx = kx + M * HID_;
    ushort_t* cx = vx + M * HID_;            // 4M elems: holds ALL FOUR W^T buffers
    ushort_t* WTq = cx;                      // 1M elems
    ushort_t* WTk = WTq + 1024 * 1024;       // 0.75M
    ushort_t* WTv = WTk + 1024 * 768;        // 0.75M
    ushort_t* WTo = WTv + 1024 * 768;        // 1M  (total 3.5M <= 4M)

    const float QSCALE = 0.125f * 1.4426950408889634f;  // 1/sqrt(D) * log2(e)

    detect_dtype<<<1, 64, 0, stream>>>((const ushort_t*)d_in[0], flag);

    // all four weight transposes in one launch
    transpose4<<<dim3(32, 32, 4), 256, 0, stream>>>(
        d_in[3], d_in[5], d_in[7], d_in[9], WTq, WTk, WTv, WTo, flag);

    G3 p;
    p.A0 = d_in[0]; p.A1 = d_in[1]; p.A2 = d_in[2];
    p.W0 = WTq;     p.W1 = WTk;     p.W2 = WTv;
    p.b0 = d_in[4]; p.b1 = d_in[6]; p.b2 = d_in[8];
    p.C0 = qx;      p.C1 = kx;      p.C2 = vx;
    p.K0 = QDIM_;   p.K1 = KDIM_;   p.K2 = VDIM_;
    p.s0 = QSCALE;  p.s1 = 1.0f;    p.s2 = 1.0f;
    const int nwg = (int)(M / 128) * (HID_ / 128);   // 256, % 8 == 0
    gemm3_mfma<<<dim3(nwg, 3), 256, 0, stream>>>(p, (int)M, HID_, flag);

    // attention: reads qx/kx/vx, writes ctx IN-PLACE into qx
    attn_mfma<<<dim3(LQ_ / 128, H_, B_), 512, 0, stream>>>(qx, kx, vx, qmask, kmask, qx);

    // O-projection: 128x64 tile -> 512 blocks (2/CU)
    gemm_one<<<dim3((int)(M / 128) * (QDIM_ / 64)), 256, 0, stream>>>(
        qx, WTo, d_in[10], d_out, (int)M, QDIM_, HID_, flag, 1.0f);
}

// Round 9
// 146.900 us; speedup vs baseline: 1.3116x; 1.3116x over previous
//
#include <hip/hip_runtime.h>
#include <hip/hip_bf16.h>

// Sizes (fixed by the problem)
#define B_   2
#define LQ_  2048
#define LK_  2048
#define QDIM_ 1024
#define KDIM_ 768
#define VDIM_ 768
#define HID_ 1024
#define H_   16
#define D_   64   // head dim

typedef unsigned short ushort_t;
typedef __attribute__((ext_vector_type(8))) short short8v;   // 8 bf16 MFMA A/B frag
typedef __attribute__((ext_vector_type(4))) float f32x4;     // MFMA C/D frag

__device__ __forceinline__ float bf2f(unsigned short u) {
    union { unsigned int i; float f; } x; x.i = ((unsigned int)u) << 16; return x.f;
}
__device__ __forceinline__ unsigned short f2bf(float f) {
    union { float f; unsigned int i; } x; x.f = f;
    unsigned int r = x.i + 0x7FFFu + ((x.i >> 16) & 1u);  // RNE
    return (unsigned short)(r >> 16);
}
__device__ __forceinline__ float exp2_(float x) {
#if defined(__has_builtin) && __has_builtin(__builtin_amdgcn_exp2f)
    return __builtin_amdgcn_exp2f(x);
#else
    return __expf(x * 0.69314718055994531f);
#endif
}
__device__ __forceinline__ unsigned cvtpk_bf16(float lo, float hi) {
    unsigned r;
    asm("v_cvt_pk_bf16_f32 %0, %1, %2" : "=v"(r) : "v"(lo), "v"(hi));
    return r;
}
__device__ __forceinline__ unsigned perm_b32(unsigned hi, unsigned lo, unsigned sel) {
#if defined(__has_builtin) && __has_builtin(__builtin_amdgcn_perm)
    return __builtin_amdgcn_perm(hi, lo, sel);
#else
    unsigned r = 0;
    for (int i = 0; i < 4; ++i) {
        unsigned s = (sel >> (8 * i)) & 0xFF;
        unsigned byte = (s < 4) ? ((lo >> (8 * s)) & 0xFF) : ((hi >> (8 * (s - 4))) & 0xFF);
        r |= byte << (8 * i);
    }
    return r;
#endif
}
// global -> LDS direct (16B per lane). Fallback: plain copy.
__device__ __forceinline__ void stage16(const ushort_t* g, ushort_t* l) {
#if defined(__has_builtin) && __has_builtin(__builtin_amdgcn_global_load_lds)
    __builtin_amdgcn_global_load_lds(
        (const __attribute__((address_space(1))) unsigned*)g,
        (__attribute__((address_space(3))) unsigned*)l, 16, 0, 0);
#else
    *(uint4*)l = *(const uint4*)g;
#endif
}

// ---------------------------------------------------------------------------
// Runtime dtype detection (flag=1 -> inputs bf16, flag=0 -> f32).
// ---------------------------------------------------------------------------
__global__ void detect_dtype(const ushort_t* __restrict__ q, int* __restrict__ flag) {
    const int tid = threadIdx.x;
    float m = 0.f;
    for (int i = tid; i < 4096; i += 64) m = fmaxf(m, fabsf(bf2f(q[i])));
    #pragma unroll
    for (int off = 1; off < 64; off <<= 1) m = fmaxf(m, __shfl_xor(m, off));
    if (tid == 0) flag[0] = (m < 1000.0f) ? 1 : 0;
}

// ---------------------------------------------------------------------------
// Fused 4-way transpose: op z: W[R][1024] (f32/bf16 per flag) -> WT[1024][R].
// ops: 0=Wq(R=1024) 1=Wk(768) 2=Wv(768) 3=Wo(1024)
// ---------------------------------------------------------------------------
__global__ __launch_bounds__(256) void transpose4(
    const void* __restrict__ W0, const void* __restrict__ W1,
    const void* __restrict__ W2, const void* __restrict__ W3,
    ushort_t* __restrict__ O0, ushort_t* __restrict__ O1,
    ushort_t* __restrict__ O2, ushort_t* __restrict__ O3,
    const int* __restrict__ flagp)
{
    __shared__ ushort_t tile[32][33];
    const int isbf = flagp[0];
    const int op = blockIdx.z;
    const void* in = (op == 0) ? W0 : (op == 1) ? W1 : (op == 2) ? W2 : W3;
    ushort_t* out  = (op == 0) ? O0 : (op == 1) ? O1 : (op == 2) ? O2 : O3;
    const int R = (op == 1 || op == 2) ? KDIM_ : 1024;
    const int C = 1024;
    const int tx = threadIdx.x & 31;
    const int ty = threadIdx.x >> 5;
    const int r0 = blockIdx.y * 32, c0 = blockIdx.x * 32;
    if (r0 >= R) return;
    #pragma unroll
    for (int j = 0; j < 4; ++j) {
        int r = r0 + ty + j * 8;
        ushort_t v;
        if (isbf) v = ((const ushort_t*)in)[(size_t)r * C + c0 + tx];
        else      v = f2bf(((const float*)in)[(size_t)r * C + c0 + tx]);
        tile[ty + j * 8][tx] = v;
    }
    __syncthreads();
    #pragma unroll
    for (int j = 0; j < 4; ++j) {
        int c = c0 + ty + j * 8;
        out[(size_t)c * R + r0 + tx] = tile[tx][ty + j * 8];
    }
}

// ---------------------------------------------------------------------------
// GEMM core, 2-phase double-buffered, tile 128xTBN, BK=32, 256 thr = 4 waves
// (2x2), wave tile 64x(TBN/2). LDS XOR-swizzled (row&3 on 8-col chunks):
// pre-swizzled gload_lds source, swizzled reads.
// ---------------------------------------------------------------------------
template<int TBN>
__device__ __forceinline__ void gemm_core(
    const void* __restrict__ A, const ushort_t* __restrict__ WT,
    const void* __restrict__ bias, void* __restrict__ Cp,
    int M, int N, int K, int isbf, int a_bf, int c_bf, float out_scale,
    int wg, ushort_t (*As)[32], ushort_t (*Bs)[32])
{
    constexpr int NF = TBN / 32;              // B frags per wave
    const int tid = threadIdx.x;
    const int l = tid & 63, w = tid >> 6;
    const int g = l >> 4, q = l & 15;
    const int wr = (w >> 1) * 64, wc = (w & 1) * (TBN / 2);
    const int nbn = N / TBN;
    const int bm = (wg / nbn) * 128;
    const int bn = (wg % nbn) * TBN;

    const int r_ = tid >> 2;                    // 0..63
    const int c_ = tid & 3;                     // 8-col chunk
    const int sc_ = ((c_ ^ (r_ & 3)) << 3);     // swizzled col
    const int dc_ = c_ << 3;

    f32x4 acc[4][NF];
    #pragma unroll
    for (int i = 0; i < 4; ++i)
        #pragma unroll
        for (int j = 0; j < NF; ++j)
            acc[i][j] = (f32x4){0.f, 0.f, 0.f, 0.f};

    const int NT = K >> 5;
    float4 fA[4];

    auto issue = [&](int t, int buf) {
        const int koff = t << 5;
        if (a_bf) {
            stage16((const ushort_t*)A + (size_t)(bm + r_) * K + koff + sc_,
                    &As[(buf << 7) + r_][dc_]);
            stage16((const ushort_t*)A + (size_t)(bm + 64 + r_) * K + koff + sc_,
                    &As[(buf << 7) + 64 + r_][dc_]);
        } else {
            const float* Af0 = (const float*)A + (size_t)(bm + r_) * K + koff + dc_;
            const float* Af1 = (const float*)A + (size_t)(bm + 64 + r_) * K + koff + dc_;
            fA[0] = *(const float4*)Af0; fA[1] = *(const float4*)(Af0 + 4);
            fA[2] = *(const float4*)Af1; fA[3] = *(const float4*)(Af1 + 4);
        }
        stage16(WT + (size_t)(bn + r_) * K + koff + sc_, &Bs[buf * TBN + r_][dc_]);
        if (TBN == 128)
            stage16(WT + (size_t)(bn + 64 + r_) * K + koff + sc_, &Bs[buf * TBN + 64 + r_][dc_]);
    };
    auto commitA = [&](int buf) {
        ushort_t t0[8], t1[8];
        t0[0]=f2bf(fA[0].x); t0[1]=f2bf(fA[0].y); t0[2]=f2bf(fA[0].z); t0[3]=f2bf(fA[0].w);
        t0[4]=f2bf(fA[1].x); t0[5]=f2bf(fA[1].y); t0[6]=f2bf(fA[1].z); t0[7]=f2bf(fA[1].w);
        t1[0]=f2bf(fA[2].x); t1[1]=f2bf(fA[2].y); t1[2]=f2bf(fA[2].z); t1[3]=f2bf(fA[2].w);
        t1[4]=f2bf(fA[3].x); t1[5]=f2bf(fA[3].y); t1[6]=f2bf(fA[3].z); t1[7]=f2bf(fA[3].w);
        *(uint4*)&As[(buf << 7) + r_][sc_]      = *(uint4*)t0;
        *(uint4*)&As[(buf << 7) + 64 + r_][sc_] = *(uint4*)t1;
    };

    issue(0, 0);
    if (!a_bf) commitA(0);
    __syncthreads();

    int cur = 0;
    const int fcol = ((g ^ (q & 3)) << 3);   // frag read col (swizzled)
    for (int t = 0; t < NT; ++t) {
        const bool has = (t + 1 < NT);
        if (has) issue(t + 1, cur ^ 1);

        short8v a[4], bb[NF];
        #pragma unroll
        for (int mf = 0; mf < 4; ++mf)
            a[mf] = *(const short8v*)&As[(cur << 7) + wr + mf * 16 + q][fcol];
        #pragma unroll
        for (int nf = 0; nf < NF; ++nf)
            bb[nf] = *(const short8v*)&Bs[cur * TBN + wc + nf * 16 + q][fcol];
        #pragma unroll
        for (int mf = 0; mf < 4; ++mf)
            #pragma unroll
            for (int nf = 0; nf < NF; ++nf)
                acc[mf][nf] = __builtin_amdgcn_mfma_f32_16x16x32_bf16(a[mf], bb[nf], acc[mf][nf], 0, 0, 0);

        if (has && !a_bf) commitA(cur ^ 1);
        __syncthreads();
        cur ^= 1;
    }

    // epilogue: D layout col=lane&15, row=(lane>>4)*4+reg
    float bv[NF];
    #pragma unroll
    for (int nf = 0; nf < NF; ++nf) {
        int col = bn + wc + nf * 16 + q;
        bv[nf] = isbf ? bf2f(((const ushort_t*)bias)[col]) : ((const float*)bias)[col];
    }
    #pragma unroll
    for (int mf = 0; mf < 4; ++mf)
        #pragma unroll
        for (int nf = 0; nf < NF; ++nf)
            #pragma unroll
            for (int reg = 0; reg < 4; ++reg) {
                int row = bm + wr + mf * 16 + g * 4 + reg;
                int col = bn + wc + nf * 16 + q;
                float vv = (acc[mf][nf][reg] + bv[nf]) * out_scale;
                if (c_bf) ((ushort_t*)Cp)[(size_t)row * N + col] = f2bf(vv);
                else      ((float*)Cp)[(size_t)row * N + col] = vv;
            }
}

struct G3 {
    const void* A0; const void* A1; const void* A2;
    const ushort_t* W0; const ushort_t* W1; const ushort_t* W2;
    const void* b0; const void* b1; const void* b2;
    void* C0; void* C1; void* C2;
    int K0, K1, K2;
    float s0, s1, s2;
};

// fused Q/K/V projections: grid (256, 3); blockIdx.y picks the op
__global__ __launch_bounds__(256) void gemm3_mfma(G3 p, int M, int N,
                                                  const int* __restrict__ flagp)
{
    __shared__ ushort_t As[2 * 128][32];
    __shared__ ushort_t Bs[2 * 128][32];
    const int isbf = flagp[0];
    const int op = blockIdx.y;
    const void* A = (op == 0) ? p.A0 : (op == 1) ? p.A1 : p.A2;
    const ushort_t* WT = (op == 0) ? p.W0 : (op == 1) ? p.W1 : p.W2;
    const void* bias = (op == 0) ? p.b0 : (op == 1) ? p.b1 : p.b2;
    void* C = (op == 0) ? p.C0 : (op == 1) ? p.C1 : p.C2;
    const int K = (op == 0) ? p.K0 : (op == 1) ? p.K1 : p.K2;
    const float sc = (op == 0) ? p.s0 : (op == 1) ? p.s1 : p.s2;
    const int cpx = gridDim.x >> 3;
    const int wg = (blockIdx.x & 7) * cpx + (blockIdx.x >> 3);
    gemm_core<128>(A, WT, bias, C, M, N, K, isbf, isbf, 1, sc, wg, As, Bs);
}

// O-projection: tile 128x64 -> 512 blocks = 2 blocks/CU
__global__ __launch_bounds__(256) void gemm_one(
    const void* __restrict__ A, const ushort_t* __restrict__ WT,
    const void* __restrict__ bias, void* __restrict__ Cp,
    int M, int N, int K, const int* __restrict__ flagp, float out_scale)
{
    __shared__ ushort_t As[2 * 128][32];
    __shared__ ushort_t Bs[2 * 64][32];
    const int isbf = flagp[0];
    const int cpx = gridDim.x >> 3;
    const int wg = (blockIdx.x & 7) * cpx + (blockIdx.x >> 3);
    gemm_core<64>(A, WT, bias, Cp, M, N, K, isbf, 1, isbf, out_scale, wg, As, Bs);
}

// ---------------------------------------------------------------------------
// MFMA flash attention (round-7 proven structure + setprio + in-place ctx).
// 512 thr = 8 waves; block = 128 q-rows; KV tiles 64, double-buffered
// 2-phase pipeline (K via gload_lds issued early; V issue-early/write-late).
// Swapped S^T = K.Q^T; PV O^T = V^T.P^T (lane-local softmax rows). Masking
// via packed-halfword AND on P (raw-score max is valid by shift-invariance).
// Denominator via ones-A-frag MFMA. Q pre-scaled by 0.125*log2(e).
// ctx written IN-PLACE over Q (block reads only the slice it writes).
// query_mask masks the KEY axis; key_mask masks the QUERY axis (faithful).
// ---------------------------------------------------------------------------
__global__ __launch_bounds__(512, 4) void attn_mfma(
    const ushort_t* __restrict__ Q, const ushort_t* __restrict__ Kp,
    const ushort_t* __restrict__ Vp, const int* __restrict__ qmask,
    const int* __restrict__ kmask, ushort_t* __restrict__ ctx)   // ctx may alias Q
{
    __shared__ ushort_t sQ[128][64];
    __shared__ ushort_t sK[2][64][64];
    __shared__ ushort_t sVt[2][64][64];   // [d][key], swizzled
    __shared__ ushort_t sP[8][16][64];    // per-wave P, swizzled
    __shared__ unsigned sMaskPk[2][32];   // packed halfword mask per key-pair

    const int tid = threadIdx.x;
    const int l = tid & 63, w = tid >> 6;   // 8 waves
    const int g = l >> 4, q = l & 15;
    const int b = blockIdx.z, h = blockIdx.y;
    const int q0 = blockIdx.x * 128;
    const size_t hoff = (size_t)h * 64;
    const int swz = (q & 7) << 3;

    // V staging map: 256 pair-chunks (2 keys x 8 d), split across 2 threads
    const int vpi = tid & 255;
    const int vk2 = (vpi & 31) * 2;
    const int vdb = vpi >> 5;             // 0..7
    const int vds = (tid >> 8) * 4;       // 0 or 4

    const int krow = tid >> 3, ks = tid & 7;
    const int kscol = ((ks ^ (krow & 7)) << 3);

    // ---- prologue: stage Q (128x64), K/V tile 0, mask tile 0 ----
    #pragma unroll
    for (int i = 0; i < 2; ++i) {
        int chunk = tid + 512 * i;
        int row = chunk >> 3, s = chunk & 7;
        stage16(Q + ((size_t)(b * LQ_) + q0 + row) * HID_ + hoff + ((s ^ (row & 7)) << 3),
                &sQ[row][s << 3]);
    }
    stage16(Kp + ((size_t)(b * LK_) + krow) * HID_ + hoff + kscol, &sK[0][krow][ks << 3]);
    {
        size_t basev = ((size_t)(b * LK_) + vk2) * HID_ + hoff + vdb * 8 + vds;
        uint2 va = *(const uint2*)(Vp + basev);
        uint2 vb2 = *(const uint2*)(Vp + basev + HID_);
        #pragma unroll
        for (int t2 = 0; t2 < 2; ++t2) {
            unsigned d0w = t2 ? va.y : va.x;
            unsigned d1w = t2 ? vb2.y : vb2.x;
            unsigned lo = perm_b32(d1w, d0w, 0x05040100);
            unsigned hi = perm_b32(d1w, d0w, 0x07060302);
            int dr0 = vdb * 8 + vds + 2 * t2, dr1 = dr0 + 1;
            *(unsigned*)&sVt[0][dr0][vk2 ^ ((dr0 & 7) << 3)] = lo;
            *(unsigned*)&sVt[0][dr1][vk2 ^ ((dr1 & 7) << 3)] = hi;
        }
    }
    if (w == 0) {
        unsigned long long bits = __ballot(qmask[b * LQ_ + l] != 0);
        if (l < 32) {
            unsigned dw = (((bits >> (2 * l)) & 1ull) ? 0xFFFFu : 0u)
                        | (((bits >> (2 * l + 1)) & 1ull) ? 0xFFFF0000u : 0u);
            sMaskPk[0][l] = dw;
        }
    }
    __syncthreads();

    const int myq = 16 * w + q;
    short8v qf0 = *(const short8v*)&sQ[myq][(g << 3) ^ swz];
    short8v qf1 = *(const short8v*)&sQ[myq][(32 + (g << 3)) ^ swz];
    const int rowm = kmask[b * LK_ + q0 + myq];

    short8v ones;
    #pragma unroll
    for (int j = 0; j < 8; ++j) ones[j] = (short)0x3F80;   // 1.0bf16

    float m_run = -1e30f;
    f32x4 o[4], o4;
    #pragma unroll
    for (int df = 0; df < 4; ++df) o[df] = (f32x4){0.f, 0.f, 0.f, 0.f};
    o4 = (f32x4){0.f, 0.f, 0.f, 0.f};

    int cur = 0;
    for (int t0 = 0; t0 < LK_; t0 += 64) {
        const int t0n = t0 + 64;
        const bool has = (t0n < LK_);
        uint2 va, vb2;
        if (has) {   // issue-early: V->regs, K gload_lds, next tile's mask
            size_t basev = ((size_t)(b * LK_) + t0n + vk2) * HID_ + hoff + vdb * 8 + vds;
            va = *(const uint2*)(Vp + basev);
            vb2 = *(const uint2*)(Vp + basev + HID_);
            stage16(Kp + ((size_t)(b * LK_) + t0n + krow) * HID_ + hoff + kscol,
                    &sK[cur ^ 1][krow][ks << 3]);
            if (w == 0) {
                unsigned long long bits = __ballot(qmask[b * LQ_ + t0n + l] != 0);
                if (l < 32) {
                    unsigned dw = (((bits >> (2 * l)) & 1ull) ? 0xFFFFu : 0u)
                                | (((bits >> (2 * l + 1)) & 1ull) ? 0xFFFF0000u : 0u);
                    sMaskPk[cur ^ 1][l] = dw;
                }
            }
        }

        // ---- S^T = K . Q^T on buffer cur ----
        f32x4 s4[4];
        #pragma unroll
        for (int kf = 0; kf < 4; ++kf) s4[kf] = (f32x4){0.f, 0.f, 0.f, 0.f};
        __builtin_amdgcn_s_setprio(1);
        #pragma unroll
        for (int kf = 0; kf < 4; ++kf) {
            short8v k0f = *(const short8v*)&sK[cur][kf * 16 + q][(g << 3) ^ swz];
            short8v k1f = *(const short8v*)&sK[cur][kf * 16 + q][(32 + (g << 3)) ^ swz];
            s4[kf] = __builtin_amdgcn_mfma_f32_16x16x32_bf16(k0f, qf0, s4[kf], 0, 0, 0);
            s4[kf] = __builtin_amdgcn_mfma_f32_16x16x32_bf16(k1f, qf1, s4[kf], 0, 0, 0);
        }
        __builtin_amdgcn_s_setprio(0);

        // ---- online softmax on RAW scores (mask applied later to P) ----
        float tmx[8];
        #pragma unroll
        for (int i = 0; i < 8; ++i) tmx[i] = fmaxf(s4[i >> 2][i & 3], s4[2 + (i >> 2)][i & 3]);
        #pragma unroll
        for (int st = 4; st >= 1; st >>= 1)
            #pragma unroll
            for (int i = 0; i < st; ++i) tmx[i] = fmaxf(tmx[i], tmx[i + st]);
        float lm = tmx[0];
        lm = fmaxf(lm, __shfl_xor(lm, 16));
        lm = fmaxf(lm, __shfl_xor(lm, 32));

        const bool fullp = __any(lm - m_run > 8.0f) != 0;   // defer-max (T13)
        float mnew, corr;
        if (fullp) { mnew = fmaxf(m_run, lm); corr = exp2_(m_run - mnew); }
        else       { mnew = m_run;            corr = 1.0f; }

        #pragma unroll
        for (int kf = 0; kf < 4; ++kf)
            #pragma unroll
            for (int reg = 0; reg < 4; ++reg)
                s4[kf][reg] = exp2_(s4[kf][reg] - mnew);    // P in-place
        m_run = mnew;

        #pragma unroll
        for (int kf = 0; kf < 4; ++kf) {
            uint2 pv;
            pv.x = cvtpk_bf16(s4[kf][0], s4[kf][1]);
            pv.y = cvtpk_bf16(s4[kf][2], s4[kf][3]);
            *(uint2*)&sP[w][q][(kf * 16 + g * 4) ^ swz] = pv;
        }

        if (fullp) {   // lane-local rescale (O^T layout: no shuffles)
            #pragma unroll
            for (int df = 0; df < 4; ++df)
                #pragma unroll
                for (int reg = 0; reg < 4; ++reg) o[df][reg] *= corr;
            #pragma unroll
            for (int reg = 0; reg < 4; ++reg) o4[reg] *= corr;
        }

        // ---- PV (swapped): O^T = V^T . P_masked^T ; denom via ones A-frag ----
        #pragma unroll
        for (int s2 = 0; s2 < 2; ++s2) {
            uint4 paw = *(const uint4*)&sP[w][q][((s2 * 32) + (g << 3)) ^ swz];
            uint4 mk = *(const uint4*)&sMaskPk[cur][s2 * 16 + g * 4];
            paw.x &= mk.x; paw.y &= mk.y; paw.z &= mk.z; paw.w &= mk.w;
            short8v pa;
            __builtin_memcpy(&pa, &paw, 16);
            __builtin_amdgcn_s_setprio(1);
            #pragma unroll
            for (int df = 0; df < 4; ++df) {
                short8v vb = *(const short8v*)&sVt[cur][df * 16 + q][((s2 * 32) + (g << 3)) ^ swz];
                o[df] = __builtin_amdgcn_mfma_f32_16x16x32_bf16(vb, pa, o[df], 0, 0, 0);
            }
            o4 = __builtin_amdgcn_mfma_f32_16x16x32_bf16(ones, pa, o4, 0, 0, 0);
            __builtin_amdgcn_s_setprio(0);
        }

        if (has) {   // write-late: V regs -> sVt[next]
            #pragma unroll
            for (int t2 = 0; t2 < 2; ++t2) {
                unsigned d0w = t2 ? va.y : va.x;
                unsigned d1w = t2 ? vb2.y : vb2.x;
                unsigned lo = perm_b32(d1w, d0w, 0x05040100);
                unsigned hi = perm_b32(d1w, d0w, 0x07060302);
                int dr0 = vdb * 8 + vds + 2 * t2, dr1 = dr0 + 1;
                *(unsigned*)&sVt[cur ^ 1][dr0][vk2 ^ ((dr0 & 7) << 3)] = lo;
                *(unsigned*)&sVt[cur ^ 1][dr1][vk2 ^ ((dr1 & 7) << 3)] = hi;
            }
        }
        __syncthreads();
        cur ^= 1;
    }

    // ---- epilogue: outputs belong to row myq; denom lane-local in o4 ----
    const float lr = o4[0];
    const float lqv = (rowm != 0 && lr > 0.f) ? (1.f / lr) : 0.f;
    ushort_t* orow = ctx + ((size_t)(b * LQ_) + q0 + myq) * HID_ + hoff;
    #pragma unroll
    for (int df = 0; df < 4; ++df) {
        uint2 st;
        st.x = cvtpk_bf16(o[df][0] * lqv, o[df][1] * lqv);
        st.y = cvtpk_bf16(o[df][2] * lqv, o[df][3] * lqv);
        *(uint2*)(orow + df * 16 + g * 4) = st;
    }
}

// ---------------------------------------------------------------------------
extern "C" void kernel_launch(void* const* d_in, const int* in_sizes, int n_in,
                              void* d_out, int out_size, void* d_ws, size_t ws_size,
                              hipStream_t stream) {
    const int* qmask = (const int*)d_in[11];
    const int* kmask = (const int*)d_in[12];

    const size_t M = (size_t)B_ * LQ_;      // 4096
    int* flag = (int*)d_ws;
    ushort_t* qx = (ushort_t*)((char*)d_ws + 256);   // Q-proj out, then ctx (in-place)
    ushort_t* kx = qx + M * HID_;
    ushort_t* vx = kx + M * HID_;
    ushort_t* cx = vx + M * HID_;            // 4M elems: holds ALL FOUR W^T buffers
    ushort_t* WTq = cx;                      // 1M elems
    ushort_t* WTk = WTq + 1024 * 1024;       // 0.75M
    ushort_t* WTv = WTk + 1024 * 768;        // 0.75M
    ushort_t* WTo = WTv + 1024 * 768;        // 1M  (total 3.5M <= 4M)

    const float QSCALE = 0.125f * 1.4426950408889634f;  // 1/sqrt(D) * log2(e)

    detect_dtype<<<1, 64, 0, stream>>>((const ushort_t*)d_in[0], flag);

    // all four weight transposes in one launch
    transpose4<<<dim3(32, 32, 4), 256, 0, stream>>>(
        d_in[3], d_in[5], d_in[7], d_in[9], WTq, WTk, WTv, WTo, flag);

    G3 p;
    p.A0 = d_in[0]; p.A1 = d_in[1]; p.A2 = d_in[2];
    p.W0 = WTq;     p.W1 = WTk;     p.W2 = WTv;
    p.b0 = d_in[4]; p.b1 = d_in[6]; p.b2 = d_in[8];
    p.C0 = qx;      p.C1 = kx;      p.C2 = vx;
    p.K0 = QDIM_;   p.K1 = KDIM_;   p.K2 = VDIM_;
    p.s0 = QSCALE;  p.s1 = 1.0f;    p.s2 = 1.0f;
    const int nwg = (int)(M / 128) * (HID_ / 128);   // 256, % 8 == 0
    gemm3_mfma<<<dim3(nwg, 3), 256, 0, stream>>>(p, (int)M, HID_, flag);

    // attention: reads qx/kx/vx, writes ctx IN-PLACE into qx
    attn_mfma<<<dim3(LQ_ / 128, H_, B_), 512, 0, stream>>>(qx, kx, vx, qmask, kmask, qx);

    // O-projection: 128x64 tile -> 512 blocks (2/CU)
    gemm_one<<<dim3((int)(M / 128) * (QDIM_ / 64)), 256, 0, stream>>>(
        qx, WTo, d_in[10], d_out, (int)M, QDIM_, HID_, flag, 1.0f);
}